// Round 1
// baseline (1753.076 us; speedup 1.0000x reference)
//
#include <hip/hip_runtime.h>
#include <math.h>

// Problem constants
#define S 2048
#define DMOD 1024
#define DK 64
#define DV 64
#define H 16
// q,k,v,attn_raw are all [S][H*64] = [2048][1024] fp32 row-major.

// ---------------------------------------------------------------------------
// init: sumexp[h*S + t] = t  (masked entries contribute exp(0)=1 each, count t)
// ---------------------------------------------------------------------------
__global__ void init_sumexp(float* __restrict__ sumexp) {
    int i = blockIdx.x * blockDim.x + threadIdx.x;
    if (i < H * S) sumexp[i] = (float)(i & (S - 1));
}

// ---------------------------------------------------------------------------
// Generic GEMM: C[M][N] = A[M][K] @ W[N][K]^T + bias[N]
// a_mode==1: A element (m,k) is  A[m*K+k] - corr[k]   (output projection)
// ---------------------------------------------------------------------------
__global__ __launch_bounds__(256) void gemm_nt(
    const float* __restrict__ A, const float* __restrict__ W,
    const float* __restrict__ bias, float* __restrict__ C,
    int M, int N, int K, int a_mode, const float* __restrict__ corr)
{
    __shared__ float As[16][65];
    __shared__ float Ws[16][65];
    const int tid = threadIdx.x;
    const int tx = tid & 15, ty = tid >> 4;
    const int m0 = blockIdx.y * 64, n0 = blockIdx.x * 64;
    float acc[4][4] = {};

    for (int k0 = 0; k0 < K; k0 += 16) {
#pragma unroll
        for (int i = 0; i < 4; ++i) {
            int e = tid + i * 256;      // 0..1023
            int m = e >> 4, kk = e & 15;
            int gk = k0 + kk;
            float av = A[(m0 + m) * K + gk];
            if (a_mode == 1) av -= corr[gk];
            As[kk][m] = av;
            Ws[kk][m] = W[(n0 + m) * K + gk];
        }
        __syncthreads();
#pragma unroll
        for (int kk = 0; kk < 16; ++kk) {
            float a[4], b[4];
#pragma unroll
            for (int i = 0; i < 4; ++i) a[i] = As[kk][ty * 4 + i];
#pragma unroll
            for (int j = 0; j < 4; ++j) b[j] = Ws[kk][tx * 4 + j];
#pragma unroll
            for (int i = 0; i < 4; ++i)
#pragma unroll
                for (int j = 0; j < 4; ++j)
                    acc[i][j] += a[i] * b[j];
        }
        __syncthreads();
    }
#pragma unroll
    for (int i = 0; i < 4; ++i) {
        int gm = m0 + ty * 4 + i;
#pragma unroll
        for (int j = 0; j < 4; ++j) {
            int gn = n0 + tx * 4 + j;
            C[gm * N + gn] = acc[i][j] + bias[gn];
        }
    }
}

// ---------------------------------------------------------------------------
// Fused attention core, per (s_tile, head):
//   attn_raw[s,:] = sum_{t<=s} (qk[s,t]/8) * v[t,:]
//   sumexp[h,t]  += sum over this block's s-rows (s>=t) of exp(qk[s,t]/8)
// ---------------------------------------------------------------------------
__global__ __launch_bounds__(256) void attn_fused(
    const float* __restrict__ q, const float* __restrict__ k,
    const float* __restrict__ v, float* __restrict__ attn_raw,
    float* __restrict__ sumexp)
{
    __shared__ float qs[64][65];
    __shared__ float ks[64][65];
    __shared__ float vs[64][65];
    __shared__ float Ps[64][65];
    __shared__ float colsum[16][64];

    const int h = blockIdx.y;
    const int s0 = blockIdx.x * 64;
    const int tid = threadIdx.x;
    const int tx = tid & 15, ty = tid >> 4;

    const float* qh = q + h * 64;   // row stride DMOD
    const float* kh = k + h * 64;
    const float* vh = v + h * 64;

    // stage q tile once: [64 s][64 d]
#pragma unroll
    for (int i = 0; i < 16; ++i) {
        int e = tid + i * 256;
        int r = e >> 6, c = e & 63;
        qs[r][c] = qh[(s0 + r) * DMOD + c];
    }

    float attn[4][4] = {};

    for (int t0 = 0; t0 <= s0; t0 += 64) {
        __syncthreads();   // protect ks/vs/Ps reuse
#pragma unroll
        for (int i = 0; i < 16; ++i) {
            int e = tid + i * 256;
            int r = e >> 6, c = e & 63;
            ks[r][c] = kh[(t0 + r) * DMOD + c];
            vs[r][c] = vh[(t0 + r) * DMOD + c];
        }
        __syncthreads();

        // x = q_tile @ k_tile^T
        float x[4][4] = {};
#pragma unroll
        for (int kk = 0; kk < 64; ++kk) {
            float a[4], b[4];
#pragma unroll
            for (int i = 0; i < 4; ++i) a[i] = qs[ty * 4 + i][kk];
#pragma unroll
            for (int j = 0; j < 4; ++j) b[j] = ks[tx * 4 + j][kk];
#pragma unroll
            for (int i = 0; i < 4; ++i)
#pragma unroll
                for (int j = 0; j < 4; ++j)
                    x[i][j] += a[i] * b[j];
        }

        // scale, mask (diagonal tile only), exp column partials
        float esum[4] = {0.f, 0.f, 0.f, 0.f};
        const bool diag = (t0 == s0);
#pragma unroll
        for (int i = 0; i < 4; ++i) {
            int s_g = s0 + ty * 4 + i;
#pragma unroll
            for (int j = 0; j < 4; ++j) {
                int t_g = t0 + tx * 4 + j;
                float xv = x[i][j] * 0.125f;
                bool masked = diag && (s_g < t_g);
                if (masked) xv = 0.f;
                else        esum[j] += __expf(xv);
                x[i][j] = xv;
            }
        }
#pragma unroll
        for (int i = 0; i < 4; ++i)
#pragma unroll
            for (int j = 0; j < 4; ++j)
                Ps[ty * 4 + i][tx * 4 + j] = x[i][j];
#pragma unroll
        for (int j = 0; j < 4; ++j) colsum[ty][tx * 4 + j] = esum[j];
        __syncthreads();

        // attn += P @ v_tile
#pragma unroll
        for (int tt = 0; tt < 64; ++tt) {
            float a[4], b[4];
#pragma unroll
            for (int i = 0; i < 4; ++i) a[i] = Ps[ty * 4 + i][tt];
#pragma unroll
            for (int j = 0; j < 4; ++j) b[j] = vs[tt][tx * 4 + j];
#pragma unroll
            for (int i = 0; i < 4; ++i)
#pragma unroll
                for (int j = 0; j < 4; ++j)
                    attn[i][j] += a[i] * b[j];
        }
        // column expsum reduce + global accumulate
        if (tid < 64) {
            float ssum = 0.f;
#pragma unroll
            for (int yy = 0; yy < 16; ++yy) ssum += colsum[yy][tid];
            atomicAdd(&sumexp[h * S + t0 + tid], ssum);
        }
    }

    // write attn_raw tile: [S][H*64] layout, head column block
    float* ah = attn_raw + h * 64;
#pragma unroll
    for (int i = 0; i < 4; ++i) {
        int s_g = s0 + ty * 4 + i;
#pragma unroll
        for (int j = 0; j < 4; ++j)
            ah[s_g * DMOD + tx * 4 + j] = attn[i][j];
    }
}

// ---------------------------------------------------------------------------
// lse = log(sumexp), in place
// ---------------------------------------------------------------------------
__global__ void lse_kernel(float* __restrict__ sumexp) {
    int i = blockIdx.x * blockDim.x + threadIdx.x;
    if (i < H * S) sumexp[i] = logf(sumexp[i]);
}

// ---------------------------------------------------------------------------
// corr[h][j] = sum_t lse[h,t] * v[t, h*64+j]
// ---------------------------------------------------------------------------
__global__ __launch_bounds__(256) void corr_kernel(
    const float* __restrict__ lse, const float* __restrict__ v,
    float* __restrict__ corr)
{
    __shared__ float red[4][64];
    const int h = blockIdx.x;
    const int tid = threadIdx.x;
    const int j = tid & 63, g = tid >> 6;
    float s = 0.f;
    for (int t = g; t < S; t += 4)
        s += lse[h * S + t] * v[t * DMOD + h * 64 + j];
    red[g][j] = s;
    __syncthreads();
    if (tid < 64)
        corr[h * 64 + tid] = red[0][tid] + red[1][tid] + red[2][tid] + red[3][tid];
}

// ---------------------------------------------------------------------------
extern "C" void kernel_launch(void* const* d_in, const int* in_sizes, int n_in,
                              void* d_out, int out_size, void* d_ws, size_t ws_size,
                              hipStream_t stream) {
    const float* Qin = (const float*)d_in[0];
    const float* Kin = (const float*)d_in[1];
    const float* Vin = (const float*)d_in[2];
    const float* WQw = (const float*)d_in[3];
    const float* WQb = (const float*)d_in[4];
    const float* WKw = (const float*)d_in[5];
    const float* WKb = (const float*)d_in[6];
    const float* WVw = (const float*)d_in[7];
    const float* WVb = (const float*)d_in[8];
    const float* WOw = (const float*)d_in[9];
    const float* WOb = (const float*)d_in[10];
    float* out = (float*)d_out;

    const size_t SZ = (size_t)S * DMOD;   // 2,097,152
    float* ws = (float*)d_ws;
    float* q        = ws;
    float* k        = ws + SZ;
    float* v        = ws + 2 * SZ;
    float* attn_raw = ws + 3 * SZ;
    float* sumexp   = ws + 4 * SZ;            // H*S = 32768
    float* corr     = ws + 4 * SZ + H * S;    // H*64 = 1024

    init_sumexp<<<(H * S + 255) / 256, 256, 0, stream>>>(sumexp);

    dim3 ggrid(DMOD / 64, S / 64);  // (16, 32)
    gemm_nt<<<ggrid, 256, 0, stream>>>(Qin, WQw, WQb, q, S, DMOD, DMOD, 0, nullptr);
    gemm_nt<<<ggrid, 256, 0, stream>>>(Kin, WKw, WKb, k, S, DMOD, DMOD, 0, nullptr);
    gemm_nt<<<ggrid, 256, 0, stream>>>(Vin, WVw, WVb, v, S, DMOD, DMOD, 0, nullptr);

    attn_fused<<<dim3(S / 64, H), 256, 0, stream>>>(q, k, v, attn_raw, sumexp);

    lse_kernel<<<(H * S + 255) / 256, 256, 0, stream>>>(sumexp);
    corr_kernel<<<H, 256, 0, stream>>>(sumexp, v, corr);

    gemm_nt<<<ggrid, 256, 0, stream>>>(attn_raw, WOw, WOb, out, S, DMOD, DMOD, 1, corr);
}

// Round 2
// 398.228 us; speedup vs baseline: 4.4022x; 4.4022x over previous
//
#include <hip/hip_runtime.h>
#include <math.h>
#include <stdint.h>

#define S 2048
#define DMOD 1024
#define H 16

typedef unsigned short ushort_t;
typedef short bf16x8 __attribute__((ext_vector_type(8)));
typedef float f32x4 __attribute__((ext_vector_type(4)));

__device__ __forceinline__ ushort_t f2b(float f) {
    union { float f; unsigned u; } x; x.f = f;
    return (ushort_t)((x.u + 0x7FFFu + ((x.u >> 16) & 1u)) >> 16);
}
__device__ __forceinline__ float b2f(ushort_t b) {
    union { unsigned u; float f; } x; x.u = ((unsigned)b) << 16;
    return x.f;
}
// async global->LDS, 16B per lane. LDS dest must be wave-uniform-base + lane*16.
__device__ __forceinline__ void gld16(const ushort_t* g, ushort_t* l) {
    __builtin_amdgcn_global_load_lds(
        (const __attribute__((address_space(1))) unsigned int*)g,
        (__attribute__((address_space(3))) unsigned int*)l, 16, 0, 0);
}

// ---------------------------------------------------------------------------
// sumexp[h*S + t] = t  (each masked (s<t) entry contributes exp(0)=1)
// ---------------------------------------------------------------------------
__global__ void init_sumexp(float* __restrict__ sumexp) {
    int i = blockIdx.x * blockDim.x + threadIdx.x;
    if (i < H * S) sumexp[i] = (float)(i & (S - 1));
}

// ---------------------------------------------------------------------------
// fp32 -> bf16 for 3 inputs (2M each, 2 segs) + 4 weights (1M each, 1 seg)
// ---------------------------------------------------------------------------
__global__ __launch_bounds__(256) void convert_all(
    const float* q, const float* k, const float* v,
    const float* wq, const float* wk, const float* wv, const float* wo,
    ushort_t* qo, ushort_t* ko, ushort_t* vo,
    ushort_t* wqo, ushort_t* wko, ushort_t* wvo, ushort_t* woo)
{
    const int seg = blockIdx.y;
    const float* src; ushort_t* dst; size_t off = 0;
    const size_t M1 = (size_t)1 << 20;
    if (seg < 2)       { src = q;  dst = qo;  off = (size_t)seg * M1; }
    else if (seg < 4)  { src = k;  dst = ko;  off = (size_t)(seg - 2) * M1; }
    else if (seg < 6)  { src = v;  dst = vo;  off = (size_t)(seg - 4) * M1; }
    else if (seg == 6) { src = wq; dst = wqo; }
    else if (seg == 7) { src = wk; dst = wko; }
    else if (seg == 8) { src = wv; dst = wvo; }
    else               { src = wo; dst = woo; }
    size_t i = off + ((size_t)blockIdx.x * 256 + threadIdx.x) * 4;
    float4 f = *(const float4*)(src + i);
    union { uint2 u2; ushort_t us[4]; } o;
    o.us[0] = f2b(f.x); o.us[1] = f2b(f.y); o.us[2] = f2b(f.z); o.us[3] = f2b(f.w);
    *(uint2*)(dst + i) = o.u2;
}

// ---------------------------------------------------------------------------
// bf16 MFMA GEMM: C[M=2048][N=1024] = A[M][K=1024] @ W[N][K]^T + bias[N]
// block tile 128x64, BK=64, 4 waves (2x2 of 64x32). XOR-swizzled LDS chunks.
// ---------------------------------------------------------------------------
#define BM 128
#define BN 64
#define BK 64
__global__ __launch_bounds__(256) void gemm_bf16(
    const ushort_t* __restrict__ A, const ushort_t* __restrict__ W,
    const float* __restrict__ bias, void* __restrict__ Cout, int out_fp32)
{
    __shared__ ushort_t As[BM * BK];
    __shared__ ushort_t Bs[BN * BK];
    const int tid = threadIdx.x;
    const int lane = tid & 63, wid = tid >> 6;
    const int quad = lane >> 4, l15 = lane & 15;
    const int wr = wid >> 1, wc = wid & 1;
    const int m0 = blockIdx.y * BM, n0 = blockIdx.x * BN;

    const f32x4 fzero = {0.f, 0.f, 0.f, 0.f};
    f32x4 acc[4][2];
#pragma unroll
    for (int i = 0; i < 4; ++i)
#pragma unroll
        for (int j = 0; j < 2; ++j) acc[i][j] = fzero;

    for (int k0 = 0; k0 < DMOD; k0 += BK) {
        __syncthreads();
#pragma unroll
        for (int i = 0; i < 4; ++i) {            // A: 1024 chunks
            int c = i * 256 + tid;
            int row = c >> 3, kcl = c & 7;
            gld16(A + (size_t)(m0 + row) * DMOD + k0 + ((kcl ^ (row & 7)) * 8),
                  &As[c * 8]);
        }
#pragma unroll
        for (int i = 0; i < 2; ++i) {            // B: 512 chunks
            int c = i * 256 + tid;
            int row = c >> 3, kcl = c & 7;
            gld16(W + (size_t)(n0 + row) * DMOD + k0 + ((kcl ^ (row & 7)) * 8),
                  &Bs[c * 8]);
        }
        __syncthreads();
#pragma unroll
        for (int kc = 0; kc < 2; ++kc) {
            bf16x8 af[4], bfr[2];
#pragma unroll
            for (int mi = 0; mi < 4; ++mi) {
                int row = wr * 64 + mi * 16 + l15;
                af[mi] = *(const bf16x8*)&As[row * BK + (((kc * 4 + quad) ^ (row & 7)) * 8)];
            }
#pragma unroll
            for (int ni = 0; ni < 2; ++ni) {
                int row = wc * 32 + ni * 16 + l15;
                bfr[ni] = *(const bf16x8*)&Bs[row * BK + (((kc * 4 + quad) ^ (row & 7)) * 8)];
            }
#pragma unroll
            for (int mi = 0; mi < 4; ++mi)
#pragma unroll
                for (int ni = 0; ni < 2; ++ni)
                    acc[mi][ni] = __builtin_amdgcn_mfma_f32_16x16x32_bf16(
                        af[mi], bfr[ni], acc[mi][ni], 0, 0, 0);
        }
    }
#pragma unroll
    for (int mi = 0; mi < 4; ++mi) {
#pragma unroll
        for (int ni = 0; ni < 2; ++ni) {
            int gn = n0 + wc * 32 + ni * 16 + l15;
            float bv = bias[gn];
#pragma unroll
            for (int r = 0; r < 4; ++r) {
                int gm = m0 + wr * 64 + mi * 16 + quad * 4 + r;
                float val = acc[mi][ni][r] + bv;
                if (out_fp32) ((float*)Cout)[(size_t)gm * DMOD + gn] = val;
                else          ((ushort_t*)Cout)[(size_t)gm * DMOD + gn] = f2b(val);
            }
        }
    }
}

// ---------------------------------------------------------------------------
// MFMA attention core per (s-tile 64, head):
//   attn_raw[s, h*64+:] = sum_{t<=s} (qk/8)[s,t] * v[t,:]   (fp32 out)
//   sumexp[h,t]        += sum_{s>=t in tile} exp(qk[s,t]/8)
// ---------------------------------------------------------------------------
__global__ __launch_bounds__(256) void attn_mfma(
    const ushort_t* __restrict__ qb, const ushort_t* __restrict__ kb,
    const ushort_t* __restrict__ vb, float* __restrict__ attn_raw,
    float* __restrict__ sumexp)
{
    __shared__ ushort_t Qs[64 * 64];   // [s][k], chunk-swizzled
    __shared__ ushort_t Ks[64 * 64];   // [t][k], chunk-swizzled
    __shared__ ushort_t Vt[64 * 64];   // [v][t], element swizz t^(((v>>2)&3)<<4)
    __shared__ ushort_t Ps[64 * 64];   // [s][t], element swizz t^(((s>>2)&3)<<4)

    const int h = blockIdx.y;
    const int s0 = (int)(gridDim.x - 1 - blockIdx.x) * 64;  // long blocks first
    const int tid = threadIdx.x;
    const int lane = tid & 63, w = tid >> 6;
    const int quad = lane >> 4, l15 = lane & 15;

    const ushort_t* qh = qb + h * 64;
    const ushort_t* kh = kb + h * 64;
    const ushort_t* vh = vb + h * 64;

    // stage Q once (async, swizzled)
#pragma unroll
    for (int i = 0; i < 2; ++i) {
        int c = i * 256 + tid;
        int row = c >> 3, kcl = c & 7;
        gld16(qh + (size_t)(s0 + row) * DMOD + ((kcl ^ (row & 7)) * 8), &Qs[c * 8]);
    }

    const f32x4 fzero = {0.f, 0.f, 0.f, 0.f};
    f32x4 oacc[4];
#pragma unroll
    for (int ni = 0; ni < 4; ++ni) oacc[ni] = fzero;

    for (int t0 = 0; t0 <= s0; t0 += 64) {
        __syncthreads();
        // K stage (async)
#pragma unroll
        for (int i = 0; i < 2; ++i) {
            int c = i * 256 + tid;
            int row = c >> 3, kcl = c & 7;
            gld16(kh + (size_t)(t0 + row) * DMOD + ((kcl ^ (row & 7)) * 8), &Ks[c * 8]);
        }
        // V stage transposed (manual, staggered writes)
#pragma unroll
        for (int i = 0; i < 2; ++i) {
            int c = i * 256 + tid;
            int tv = c >> 3;
            int d0 = (c & 7) * 8;
            union { uint4 q; ushort_t u[8]; } raw;
            raw.q = *(const uint4*)(vh + (size_t)(t0 + tv) * DMOD + d0);
#pragma unroll
            for (int jj = 0; jj < 8; ++jj) {
                int j = (jj + (tid & 7)) & 7;
                int d = d0 + j;
                int tsw = tv ^ (((d >> 2) & 3) << 4);
                Vt[d * 64 + tsw] = raw.u[j];
            }
        }
        __syncthreads();

        // X = Q K^T  (D[s 16][t 64] per wave)
        f32x4 xf[4];
#pragma unroll
        for (int ti = 0; ti < 4; ++ti) xf[ti] = fzero;
#pragma unroll
        for (int kc = 0; kc < 2; ++kc) {
            int rq = w * 16 + l15;
            bf16x8 aq = *(const bf16x8*)&Qs[rq * 64 + (((kc * 4 + quad) ^ (rq & 7)) * 8)];
#pragma unroll
            for (int ti = 0; ti < 4; ++ti) {
                int rk = ti * 16 + l15;
                bf16x8 bk = *(const bf16x8*)&Ks[rk * 64 + (((kc * 4 + quad) ^ (rk & 7)) * 8)];
                xf[ti] = __builtin_amdgcn_mfma_f32_16x16x32_bf16(aq, bk, xf[ti], 0, 0, 0);
            }
        }

        // scale, mask, exp column sums, P -> LDS (bf16)
        const int s_base = s0 + w * 16 + quad * 4;
        const bool diag = (t0 == s0);
#pragma unroll
        for (int ti = 0; ti < 4; ++ti) {
            int t_g = t0 + ti * 16 + l15;
            float es = 0.f;
#pragma unroll
            for (int r = 0; r < 4; ++r) {
                float xv = xf[ti][r] * 0.125f;
                bool live = (!diag) || (s_base + r >= t_g);
                xv = live ? xv : 0.f;
                es += live ? __expf(xv) : 0.f;
                xf[ti][r] = xv;
            }
            es += __shfl_xor(es, 16, 64);
            es += __shfl_xor(es, 32, 64);
            if (quad == 0) atomicAdd(&sumexp[h * S + t_g], es);
            int s_loc = w * 16 + quad * 4;
#pragma unroll
            for (int r = 0; r < 4; ++r) {
                int sl = s_loc + r;
                int tcol = ti * 16 + l15;
                int tsw = tcol ^ (((sl >> 2) & 3) << 4);
                Ps[sl * 64 + tsw] = f2b(xf[ti][r]);
            }
        }
        __syncthreads();

        // O += P V  (D[s 16][v 64] per wave)
#pragma unroll
        for (int kc = 0; kc < 2; ++kc) {
            int rp = w * 16 + l15;
            int T0 = kc * 32 + quad * 8;
            bf16x8 ap = *(const bf16x8*)&Ps[rp * 64 + (T0 ^ (((rp >> 2) & 3) << 4))];
#pragma unroll
            for (int ni = 0; ni < 4; ++ni) {
                int rv = ni * 16 + l15;
                bf16x8 bv = *(const bf16x8*)&Vt[rv * 64 + (T0 ^ (((rv >> 2) & 3) << 4))];
                oacc[ni] = __builtin_amdgcn_mfma_f32_16x16x32_bf16(ap, bv, oacc[ni], 0, 0, 0);
            }
        }
    }

#pragma unroll
    for (int ni = 0; ni < 4; ++ni)
#pragma unroll
        for (int r = 0; r < 4; ++r) {
            int s_g = s0 + w * 16 + quad * 4 + r;
            attn_raw[(size_t)s_g * DMOD + h * 64 + ni * 16 + l15] = oacc[ni][r];
        }
}

// ---------------------------------------------------------------------------
// corr[h][j] = sum_t log(sumexp[h,t]) * v_bf16[t, h*64+j]
// ---------------------------------------------------------------------------
__global__ __launch_bounds__(256) void corr_kernel(
    const float* __restrict__ sumexp, const ushort_t* __restrict__ vb,
    float* __restrict__ corr)
{
    __shared__ float red[4][64];
    const int hh = blockIdx.x;
    const int tid = threadIdx.x;
    const int j = tid & 63, g = tid >> 6;
    float s = 0.f;
    for (int t = g; t < S; t += 4)
        s += logf(sumexp[hh * S + t]) * b2f(vb[(size_t)t * DMOD + hh * 64 + j]);
    red[g][j] = s;
    __syncthreads();
    if (tid < 64)
        corr[hh * 64 + tid] = red[0][tid] + red[1][tid] + red[2][tid] + red[3][tid];
}

// ---------------------------------------------------------------------------
// Zb = bf16(attn_raw - corr[col])
// ---------------------------------------------------------------------------
__global__ __launch_bounds__(256) void convert_Z(
    const float* __restrict__ attn_raw, const float* __restrict__ corr,
    ushort_t* __restrict__ Zb)
{
    size_t i = ((size_t)blockIdx.x * 256 + threadIdx.x) * 4;
    float4 f = *(const float4*)(attn_raw + i);
    int c = (int)(i & (DMOD - 1));
    union { uint2 u2; ushort_t us[4]; } o;
    o.us[0] = f2b(f.x - corr[c]);
    o.us[1] = f2b(f.y - corr[c + 1]);
    o.us[2] = f2b(f.z - corr[c + 2]);
    o.us[3] = f2b(f.w - corr[c + 3]);
    *(uint2*)(Zb + i) = o.u2;
}

// ---------------------------------------------------------------------------
extern "C" void kernel_launch(void* const* d_in, const int* in_sizes, int n_in,
                              void* d_out, int out_size, void* d_ws, size_t ws_size,
                              hipStream_t stream) {
    const float* Qin = (const float*)d_in[0];
    const float* Kin = (const float*)d_in[1];
    const float* Vin = (const float*)d_in[2];
    const float* WQw = (const float*)d_in[3];
    const float* WQb = (const float*)d_in[4];
    const float* WKw = (const float*)d_in[5];
    const float* WKb = (const float*)d_in[6];
    const float* WVw = (const float*)d_in[7];
    const float* WVb = (const float*)d_in[8];
    const float* WOw = (const float*)d_in[9];
    const float* WOb = (const float*)d_in[10];

    float* ws = (float*)d_ws;
    const size_t M1 = (size_t)1 << 20;
    // bf16 buffers live in float-unit slots (2 bf16 per float)
    ushort_t* qbb  = (ushort_t*)(ws);                 // 1M fl
    ushort_t* kbb  = (ushort_t*)(ws + M1);            // 1M fl
    ushort_t* vbb  = (ushort_t*)(ws + 2 * M1);        // 1M fl
    ushort_t* wqb  = (ushort_t*)(ws + 3 * M1);        // 0.5M fl
    ushort_t* wkb  = (ushort_t*)(ws + 3 * M1 + M1 / 2);
    ushort_t* wvb  = (ushort_t*)(ws + 4 * M1);
    ushort_t* wob  = (ushort_t*)(ws + 4 * M1 + M1 / 2);
    ushort_t* Qbin = (ushort_t*)(ws + 5 * M1);        // 1M fl, reused as Zb
    ushort_t* Kbin = (ushort_t*)(ws + 6 * M1);        // 1M fl \ reused as
    ushort_t* Vbin = (ushort_t*)(ws + 7 * M1);        // 1M fl / attn_raw (2M fl)
    float* attn_raw = ws + 6 * M1;
    ushort_t* Zb    = (ushort_t*)(ws + 5 * M1);
    float* sumexp   = ws + 8 * M1;                    // 32768
    float* corr     = ws + 8 * M1 + H * S;            // 1024

    init_sumexp<<<(H * S + 255) / 256, 256, 0, stream>>>(sumexp);
    convert_all<<<dim3(1024, 10), 256, 0, stream>>>(
        Qin, Kin, Vin, WQw, WKw, WVw, WOw,
        Qbin, Kbin, Vbin, wqb, wkb, wvb, wob);

    dim3 gg(DMOD / BN, S / BM);  // (16,16)
    gemm_bf16<<<gg, 256, 0, stream>>>(Qbin, wqb, WQb, qbb, 0);
    gemm_bf16<<<gg, 256, 0, stream>>>(Kbin, wkb, WKb, kbb, 0);
    gemm_bf16<<<gg, 256, 0, stream>>>(Vbin, wvb, WVb, vbb, 0);

    attn_mfma<<<dim3(S / 64, H), 256, 0, stream>>>(qbb, kbb, vbb, attn_raw, sumexp);

    corr_kernel<<<H, 256, 0, stream>>>(sumexp, vbb, corr);
    convert_Z<<<2048, 256, 0, stream>>>(attn_raw, corr, Zb);

    gemm_bf16<<<gg, 256, 0, stream>>>(Zb, wob, WOb, d_out, 1);
}

// Round 3
// 285.522 us; speedup vs baseline: 6.1399x; 1.3947x over previous
//
#include <hip/hip_runtime.h>
#include <math.h>
#include <stdint.h>

#define S 2048
#define DMOD 1024
#define H 16

typedef unsigned short ushort_t;
typedef short bf16x8 __attribute__((ext_vector_type(8)));
typedef float f32x4 __attribute__((ext_vector_type(4)));

__device__ __forceinline__ ushort_t f2b(float f) {
    union { float f; unsigned u; } x; x.f = f;
    return (ushort_t)((x.u + 0x7FFFu + ((x.u >> 16) & 1u)) >> 16);
}
__device__ __forceinline__ float b2f(ushort_t b) {
    union { unsigned u; float f; } x; x.u = ((unsigned)b) << 16;
    return x.f;
}
// async global->LDS, 16B per lane. LDS dest must be wave-uniform-base + lane*16.
__device__ __forceinline__ void gld16(const ushort_t* g, ushort_t* l) {
    __builtin_amdgcn_global_load_lds(
        (const __attribute__((address_space(1))) unsigned int*)g,
        (__attribute__((address_space(3))) unsigned int*)l, 16, 0, 0);
}

// ---------------------------------------------------------------------------
// sumexp[h*S + t] = t  (each masked (s<t) entry contributes exp(0)=1)
// also zeroes corr[0..1023] which sits contiguously after sumexp.
// ---------------------------------------------------------------------------
__global__ void init_sumexp(float* __restrict__ sumexp) {
    int i = blockIdx.x * blockDim.x + threadIdx.x;
    if (i < H * S)                sumexp[i] = (float)(i & (S - 1));
    else if (i < H * S + H * 64)  sumexp[i] = 0.f;   // corr
}

// ---------------------------------------------------------------------------
// fp32 -> bf16 for 3 inputs (2M each, 2 segs) + 4 weights (1M each, 1 seg)
// ---------------------------------------------------------------------------
__global__ __launch_bounds__(256) void convert_all(
    const float* q, const float* k, const float* v,
    const float* wq, const float* wk, const float* wv, const float* wo,
    ushort_t* qo, ushort_t* ko, ushort_t* vo,
    ushort_t* wqo, ushort_t* wko, ushort_t* wvo, ushort_t* woo)
{
    const int seg = blockIdx.y;
    const float* src; ushort_t* dst; size_t off = 0;
    const size_t M1 = (size_t)1 << 20;
    if (seg < 2)       { src = q;  dst = qo;  off = (size_t)seg * M1; }
    else if (seg < 4)  { src = k;  dst = ko;  off = (size_t)(seg - 2) * M1; }
    else if (seg < 6)  { src = v;  dst = vo;  off = (size_t)(seg - 4) * M1; }
    else if (seg == 6) { src = wq; dst = wqo; }
    else if (seg == 7) { src = wk; dst = wko; }
    else if (seg == 8) { src = wv; dst = wvo; }
    else               { src = wo; dst = woo; }
    size_t i = off + ((size_t)blockIdx.x * 256 + threadIdx.x) * 4;
    float4 f = *(const float4*)(src + i);
    union { uint2 u2; ushort_t us[4]; } o;
    o.us[0] = f2b(f.x); o.us[1] = f2b(f.y); o.us[2] = f2b(f.z); o.us[3] = f2b(f.w);
    *(uint2*)(dst + i) = o.u2;
}

// ---------------------------------------------------------------------------
// bf16 MFMA GEMM: C[M=2048][N=1024] = A[M][K=1024] @ W[N][K]^T + bias[N]
// block tile 128x64, BK=64, 4 waves (2x2 of 64x32). XOR-swizzled LDS chunks.
// ---------------------------------------------------------------------------
#define BM 128
#define BN 64
#define BK 64
__global__ __launch_bounds__(256) void gemm_bf16(
    const ushort_t* __restrict__ A, const ushort_t* __restrict__ W,
    const float* __restrict__ bias, void* __restrict__ Cout, int out_fp32)
{
    __shared__ ushort_t As[BM * BK];
    __shared__ ushort_t Bs[BN * BK];
    const int tid = threadIdx.x;
    const int lane = tid & 63, wid = tid >> 6;
    const int quad = lane >> 4, l15 = lane & 15;
    const int wr = wid >> 1, wc = wid & 1;
    const int m0 = blockIdx.y * BM, n0 = blockIdx.x * BN;

    const f32x4 fzero = {0.f, 0.f, 0.f, 0.f};
    f32x4 acc[4][2];
#pragma unroll
    for (int i = 0; i < 4; ++i)
#pragma unroll
        for (int j = 0; j < 2; ++j) acc[i][j] = fzero;

    for (int k0 = 0; k0 < DMOD; k0 += BK) {
        __syncthreads();
#pragma unroll
        for (int i = 0; i < 4; ++i) {            // A: 1024 chunks
            int c = i * 256 + tid;
            int row = c >> 3, kcl = c & 7;
            gld16(A + (size_t)(m0 + row) * DMOD + k0 + ((kcl ^ (row & 7)) * 8),
                  &As[c * 8]);
        }
#pragma unroll
        for (int i = 0; i < 2; ++i) {            // B: 512 chunks
            int c = i * 256 + tid;
            int row = c >> 3, kcl = c & 7;
            gld16(W + (size_t)(n0 + row) * DMOD + k0 + ((kcl ^ (row & 7)) * 8),
                  &Bs[c * 8]);
        }
        __syncthreads();
#pragma unroll
        for (int kc = 0; kc < 2; ++kc) {
            bf16x8 af[4], bfr[2];
#pragma unroll
            for (int mi = 0; mi < 4; ++mi) {
                int row = wr * 64 + mi * 16 + l15;
                af[mi] = *(const bf16x8*)&As[row * BK + (((kc * 4 + quad) ^ (row & 7)) * 8)];
            }
#pragma unroll
            for (int ni = 0; ni < 2; ++ni) {
                int row = wc * 32 + ni * 16 + l15;
                bfr[ni] = *(const bf16x8*)&Bs[row * BK + (((kc * 4 + quad) ^ (row & 7)) * 8)];
            }
#pragma unroll
            for (int mi = 0; mi < 4; ++mi)
#pragma unroll
                for (int ni = 0; ni < 2; ++ni)
                    acc[mi][ni] = __builtin_amdgcn_mfma_f32_16x16x32_bf16(
                        af[mi], bfr[ni], acc[mi][ni], 0, 0, 0);
        }
    }
#pragma unroll
    for (int mi = 0; mi < 4; ++mi) {
#pragma unroll
        for (int ni = 0; ni < 2; ++ni) {
            int gn = n0 + wc * 32 + ni * 16 + l15;
            float bv = bias[gn];
#pragma unroll
            for (int r = 0; r < 4; ++r) {
                int gm = m0 + wr * 64 + mi * 16 + quad * 4 + r;
                float val = acc[mi][ni][r] + bv;
                if (out_fp32) ((float*)Cout)[(size_t)gm * DMOD + gn] = val;
                else          ((ushort_t*)Cout)[(size_t)gm * DMOD + gn] = f2b(val);
            }
        }
    }
}

// ---------------------------------------------------------------------------
// MFMA attention core per (s-tile 64, head):
//   attn_raw[s, h*64+:] = sum_{t<=s} (qk/8)[s,t] * v[t,:]   (fp32 out)
//   sumexp[h,t]        += sum_{s>=t in tile} exp(qk[s,t]/8)
// ---------------------------------------------------------------------------
__global__ __launch_bounds__(256) void attn_mfma(
    const ushort_t* __restrict__ qb, const ushort_t* __restrict__ kb,
    const ushort_t* __restrict__ vb, float* __restrict__ attn_raw,
    float* __restrict__ sumexp)
{
    __shared__ ushort_t Qs[64 * 64];   // [s][k], chunk-swizzled
    __shared__ ushort_t Ks[64 * 64];   // [t][k], chunk-swizzled
    __shared__ ushort_t Vt[64 * 64];   // [v][t], element swizz t^(((v>>2)&3)<<4)
    __shared__ ushort_t Ps[64 * 64];   // [s][t], element swizz t^(((s>>2)&3)<<4)

    const int h = blockIdx.y;
    const int s0 = (int)(gridDim.x - 1 - blockIdx.x) * 64;  // long blocks first
    const int tid = threadIdx.x;
    const int lane = tid & 63, w = tid >> 6;
    const int quad = lane >> 4, l15 = lane & 15;

    const ushort_t* qh = qb + h * 64;
    const ushort_t* kh = kb + h * 64;
    const ushort_t* vh = vb + h * 64;

    // stage Q once (async, swizzled)
#pragma unroll
    for (int i = 0; i < 2; ++i) {
        int c = i * 256 + tid;
        int row = c >> 3, kcl = c & 7;
        gld16(qh + (size_t)(s0 + row) * DMOD + ((kcl ^ (row & 7)) * 8), &Qs[c * 8]);
    }

    const f32x4 fzero = {0.f, 0.f, 0.f, 0.f};
    f32x4 oacc[4];
#pragma unroll
    for (int ni = 0; ni < 4; ++ni) oacc[ni] = fzero;

    for (int t0 = 0; t0 <= s0; t0 += 64) {
        __syncthreads();
        // K stage (async)
#pragma unroll
        for (int i = 0; i < 2; ++i) {
            int c = i * 256 + tid;
            int row = c >> 3, kcl = c & 7;
            gld16(kh + (size_t)(t0 + row) * DMOD + ((kcl ^ (row & 7)) * 8), &Ks[c * 8]);
        }
        // V stage transposed (manual, staggered writes)
#pragma unroll
        for (int i = 0; i < 2; ++i) {
            int c = i * 256 + tid;
            int tv = c >> 3;
            int d0 = (c & 7) * 8;
            union { uint4 q; ushort_t u[8]; } raw;
            raw.q = *(const uint4*)(vh + (size_t)(t0 + tv) * DMOD + d0);
#pragma unroll
            for (int jj = 0; jj < 8; ++jj) {
                int j = (jj + (tid & 7)) & 7;
                int d = d0 + j;
                int tsw = tv ^ (((d >> 2) & 3) << 4);
                Vt[d * 64 + tsw] = raw.u[j];
            }
        }
        __syncthreads();

        // X = Q K^T  (D[s 16][t 64] per wave)
        f32x4 xf[4];
#pragma unroll
        for (int ti = 0; ti < 4; ++ti) xf[ti] = fzero;
#pragma unroll
        for (int kc = 0; kc < 2; ++kc) {
            int rq = w * 16 + l15;
            bf16x8 aq = *(const bf16x8*)&Qs[rq * 64 + (((kc * 4 + quad) ^ (rq & 7)) * 8)];
#pragma unroll
            for (int ti = 0; ti < 4; ++ti) {
                int rk = ti * 16 + l15;
                bf16x8 bk = *(const bf16x8*)&Ks[rk * 64 + (((kc * 4 + quad) ^ (rk & 7)) * 8)];
                xf[ti] = __builtin_amdgcn_mfma_f32_16x16x32_bf16(aq, bk, xf[ti], 0, 0, 0);
            }
        }

        // scale, mask, exp column sums, P -> LDS (bf16)
        const int s_base = s0 + w * 16 + quad * 4;
        const bool diag = (t0 == s0);
#pragma unroll
        for (int ti = 0; ti < 4; ++ti) {
            int t_g = t0 + ti * 16 + l15;
            float es = 0.f;
#pragma unroll
            for (int r = 0; r < 4; ++r) {
                float xv = xf[ti][r] * 0.125f;
                bool live = (!diag) || (s_base + r >= t_g);
                xv = live ? xv : 0.f;
                es += live ? __expf(xv) : 0.f;
                xf[ti][r] = xv;
            }
            es += __shfl_xor(es, 16, 64);
            es += __shfl_xor(es, 32, 64);
            if (quad == 0) atomicAdd(&sumexp[h * S + t_g], es);
            int s_loc = w * 16 + quad * 4;
#pragma unroll
            for (int r = 0; r < 4; ++r) {
                int sl = s_loc + r;
                int tcol = ti * 16 + l15;
                int tsw = tcol ^ (((sl >> 2) & 3) << 4);
                Ps[sl * 64 + tsw] = f2b(xf[ti][r]);
            }
        }
        __syncthreads();

        // O += P V  (D[s 16][v 64] per wave)
#pragma unroll
        for (int kc = 0; kc < 2; ++kc) {
            int rp = w * 16 + l15;
            int T0 = kc * 32 + quad * 8;
            bf16x8 ap = *(const bf16x8*)&Ps[rp * 64 + (T0 ^ (((rp >> 2) & 3) << 4))];
#pragma unroll
            for (int ni = 0; ni < 4; ++ni) {
                int rv = ni * 16 + l15;
                bf16x8 bv = *(const bf16x8*)&Vt[rv * 64 + (T0 ^ (((rv >> 2) & 3) << 4))];
                oacc[ni] = __builtin_amdgcn_mfma_f32_16x16x32_bf16(ap, bv, oacc[ni], 0, 0, 0);
            }
        }
    }

#pragma unroll
    for (int ni = 0; ni < 4; ++ni)
#pragma unroll
        for (int r = 0; r < 4; ++r) {
            int s_g = s0 + w * 16 + quad * 4 + r;
            attn_raw[(size_t)s_g * DMOD + h * 64 + ni * 16 + l15] = oacc[ni][r];
        }
}

// ---------------------------------------------------------------------------
// corr[h][j] += sum_{t in 64-block} log(sumexp[h,t]) * v_bf16[t, h*64+j]
// grid (H, S/64) = (16, 32); corr zero-initialized by init_sumexp.
// ---------------------------------------------------------------------------
__global__ __launch_bounds__(256) void corr_kernel(
    const float* __restrict__ sumexp, const ushort_t* __restrict__ vb,
    float* __restrict__ corr)
{
    __shared__ float red[4][64];
    const int hh = blockIdx.x;
    const int t0 = blockIdx.y * 64;
    const int tid = threadIdx.x;
    const int j = tid & 63, g = tid >> 6;
    float s = 0.f;
#pragma unroll
    for (int i = 0; i < 16; ++i) {
        int t = t0 + g + i * 4;
        s += logf(sumexp[hh * S + t]) * b2f(vb[(size_t)t * DMOD + hh * 64 + j]);
    }
    red[g][j] = s;
    __syncthreads();
    if (tid < 64)
        atomicAdd(&corr[hh * 64 + tid],
                  red[0][tid] + red[1][tid] + red[2][tid] + red[3][tid]);
}

// ---------------------------------------------------------------------------
// Zb = bf16(attn_raw - corr[col])
// ---------------------------------------------------------------------------
__global__ __launch_bounds__(256) void convert_Z(
    const float* __restrict__ attn_raw, const float* __restrict__ corr,
    ushort_t* __restrict__ Zb)
{
    size_t i = ((size_t)blockIdx.x * 256 + threadIdx.x) * 4;
    float4 f = *(const float4*)(attn_raw + i);
    int c = (int)(i & (DMOD - 1));
    union { uint2 u2; ushort_t us[4]; } o;
    o.us[0] = f2b(f.x - corr[c]);
    o.us[1] = f2b(f.y - corr[c + 1]);
    o.us[2] = f2b(f.z - corr[c + 2]);
    o.us[3] = f2b(f.w - corr[c + 3]);
    *(uint2*)(Zb + i) = o.u2;
}

// ---------------------------------------------------------------------------
extern "C" void kernel_launch(void* const* d_in, const int* in_sizes, int n_in,
                              void* d_out, int out_size, void* d_ws, size_t ws_size,
                              hipStream_t stream) {
    const float* Qin = (const float*)d_in[0];
    const float* Kin = (const float*)d_in[1];
    const float* Vin = (const float*)d_in[2];
    const float* WQw = (const float*)d_in[3];
    const float* WQb = (const float*)d_in[4];
    const float* WKw = (const float*)d_in[5];
    const float* WKb = (const float*)d_in[6];
    const float* WVw = (const float*)d_in[7];
    const float* WVb = (const float*)d_in[8];
    const float* WOw = (const float*)d_in[9];
    const float* WOb = (const float*)d_in[10];

    float* ws = (float*)d_ws;
    const size_t M1 = (size_t)1 << 20;
    // bf16 buffers live in float-unit slots (2 bf16 per float)
    ushort_t* qbb  = (ushort_t*)(ws);                 // 1M fl
    ushort_t* kbb  = (ushort_t*)(ws + M1);            // 1M fl
    ushort_t* vbb  = (ushort_t*)(ws + 2 * M1);        // 1M fl
    ushort_t* wqb  = (ushort_t*)(ws + 3 * M1);        // 0.5M fl
    ushort_t* wkb  = (ushort_t*)(ws + 3 * M1 + M1 / 2);
    ushort_t* wvb  = (ushort_t*)(ws + 4 * M1);
    ushort_t* wob  = (ushort_t*)(ws + 4 * M1 + M1 / 2);
    ushort_t* Qbin = (ushort_t*)(ws + 5 * M1);        // 1M fl, reused as Zb
    ushort_t* Kbin = (ushort_t*)(ws + 6 * M1);        // 1M fl \ reused as
    ushort_t* Vbin = (ushort_t*)(ws + 7 * M1);        // 1M fl / attn_raw (2M fl)
    float* attn_raw = ws + 6 * M1;
    ushort_t* Zb    = (ushort_t*)(ws + 5 * M1);
    float* sumexp   = ws + 8 * M1;                    // 32768
    float* corr     = ws + 8 * M1 + H * S;            // 1024

    init_sumexp<<<(H * S + H * 64 + 255) / 256, 256, 0, stream>>>(sumexp);
    convert_all<<<dim3(1024, 10), 256, 0, stream>>>(
        Qin, Kin, Vin, WQw, WKw, WVw, WOw,
        Qbin, Kbin, Vbin, wqb, wkb, wvb, wob);

    dim3 gg(DMOD / BN, S / BM);  // (16,16)
    gemm_bf16<<<gg, 256, 0, stream>>>(Qbin, wqb, WQb, qbb, 0);
    gemm_bf16<<<gg, 256, 0, stream>>>(Kbin, wkb, WKb, kbb, 0);
    gemm_bf16<<<gg, 256, 0, stream>>>(Vbin, wvb, WVb, vbb, 0);

    attn_mfma<<<dim3(S / 64, H), 256, 0, stream>>>(qbb, kbb, vbb, attn_raw, sumexp);

    corr_kernel<<<dim3(H, S / 64), 256, 0, stream>>>(sumexp, vbb, corr);
    convert_Z<<<2048, 256, 0, stream>>>(attn_raw, corr, Zb);

    gemm_bf16<<<gg, 256, 0, stream>>>(Zb, wob, WOb, d_out, 1);
}

// Round 4
// 214.272 us; speedup vs baseline: 8.1815x; 1.3325x over previous
//
#include <hip/hip_runtime.h>
#include <math.h>
#include <stdint.h>

#define S 2048
#define DMOD 1024
#define H 16

typedef unsigned short ushort_t;
typedef short bf16x8 __attribute__((ext_vector_type(8)));
typedef float f32x4 __attribute__((ext_vector_type(4)));

// chunk swizzle: rows 1..7 apart and 8 apart land on different chunk columns
#define SW(r) ((((r) & 7)) ^ ((((r) >> 3) & 3) << 1))

__device__ __forceinline__ ushort_t f2b(float f) {
    union { float f; unsigned u; } x; x.f = f;
    return (ushort_t)((x.u + 0x7FFFu + ((x.u >> 16) & 1u)) >> 16);
}
__device__ __forceinline__ float b2f(ushort_t b) {
    union { unsigned u; float f; } x; x.u = ((unsigned)b) << 16;
    return x.f;
}
__device__ __forceinline__ void gld16(const ushort_t* g, ushort_t* l) {
    __builtin_amdgcn_global_load_lds(
        (const __attribute__((address_space(1))) unsigned int*)g,
        (__attribute__((address_space(3))) unsigned int*)l, 16, 0, 0);
}

// ---------------------------------------------------------------------------
__global__ void init_sumexp(float* __restrict__ sumexp) {
    int i = blockIdx.x * blockDim.x + threadIdx.x;
    if (i < H * S)               sumexp[i] = (float)(i & (S - 1));
    else if (i < H * S + H * 64) sumexp[i] = 0.f;   // corr
}

// ---------------------------------------------------------------------------
__global__ __launch_bounds__(256) void convert_all(
    const float* q, const float* k, const float* v,
    const float* wq, const float* wk, const float* wv, const float* wo,
    ushort_t* qo, ushort_t* ko, ushort_t* vo,
    ushort_t* wqo, ushort_t* wko, ushort_t* wvo, ushort_t* woo)
{
    const int seg = blockIdx.y;
    const float* src; ushort_t* dst; size_t off = 0;
    const size_t M1 = (size_t)1 << 20;
    if (seg < 2)       { src = q;  dst = qo;  off = (size_t)seg * M1; }
    else if (seg < 4)  { src = k;  dst = ko;  off = (size_t)(seg - 2) * M1; }
    else if (seg < 6)  { src = v;  dst = vo;  off = (size_t)(seg - 4) * M1; }
    else if (seg == 6) { src = wq; dst = wqo; }
    else if (seg == 7) { src = wk; dst = wko; }
    else if (seg == 8) { src = wv; dst = wvo; }
    else               { src = wo; dst = woo; }
    size_t i = off + ((size_t)blockIdx.x * 256 + threadIdx.x) * 4;
    float4 f = *(const float4*)(src + i);
    union { uint2 u2; ushort_t us[4]; } o;
    o.us[0] = f2b(f.x); o.us[1] = f2b(f.y); o.us[2] = f2b(f.z); o.us[3] = f2b(f.w);
    *(uint2*)(dst + i) = o.u2;
}

// ---------------------------------------------------------------------------
// Fused QKV projection GEMM: block tile 128x64 over N=3072 (Q|K|V).
// seg 0/1 -> bf16 store to qbb/kbb [t][1024]; seg 2 -> transposed store to
// vt [v_global 1024][t 2048] (packed 4x bf16 = 8B per store).
// ---------------------------------------------------------------------------
__global__ __launch_bounds__(256) void gemm_qkv(
    const ushort_t* __restrict__ A0, const ushort_t* __restrict__ A1,
    const ushort_t* __restrict__ A2, const ushort_t* __restrict__ Wqkv,
    const float* __restrict__ b0, const float* __restrict__ b1,
    const float* __restrict__ b2,
    ushort_t* __restrict__ qbb, ushort_t* __restrict__ kbb,
    ushort_t* __restrict__ vt)
{
    __shared__ ushort_t As[128 * 64];
    __shared__ ushort_t Bs[64 * 64];
    const int tid = threadIdx.x;
    const int lane = tid & 63, wid = tid >> 6;
    const int quad = lane >> 4, l15 = lane & 15;
    const int wr = wid >> 1, wc = wid & 1;
    const int m0 = blockIdx.y * 128;
    const int n0 = blockIdx.x * 64;
    const int seg = n0 >> 10;
    const int nloc = n0 & 1023;
    const ushort_t* A = seg == 0 ? A0 : (seg == 1 ? A1 : A2);
    const float* bias = seg == 0 ? b0 : (seg == 1 ? b1 : b2);

    const f32x4 fz = {0.f, 0.f, 0.f, 0.f};
    f32x4 acc[4][2];
#pragma unroll
    for (int i = 0; i < 4; ++i) { acc[i][0] = fz; acc[i][1] = fz; }

    for (int k0 = 0; k0 < DMOD; k0 += 64) {
        __syncthreads();
#pragma unroll
        for (int i = 0; i < 4; ++i) {
            int c = i * 256 + tid, row = c >> 3, kcl = c & 7;
            gld16(A + (size_t)(m0 + row) * DMOD + k0 + (kcl ^ SW(row)) * 8, &As[c * 8]);
        }
#pragma unroll
        for (int i = 0; i < 2; ++i) {
            int c = i * 256 + tid, row = c >> 3, kcl = c & 7;
            gld16(Wqkv + (size_t)(n0 + row) * DMOD + k0 + (kcl ^ SW(row)) * 8, &Bs[c * 8]);
        }
        __syncthreads();
#pragma unroll
        for (int kc = 0; kc < 2; ++kc) {
            bf16x8 af[4], bfr[2];
#pragma unroll
            for (int mi = 0; mi < 4; ++mi) {
                int row = wr * 64 + mi * 16 + l15;
                af[mi] = *(const bf16x8*)&As[row * 64 + ((kc * 4 + quad) ^ SW(row)) * 8];
            }
#pragma unroll
            for (int ni = 0; ni < 2; ++ni) {
                int row = wc * 32 + ni * 16 + l15;
                bfr[ni] = *(const bf16x8*)&Bs[row * 64 + ((kc * 4 + quad) ^ SW(row)) * 8];
            }
#pragma unroll
            for (int mi = 0; mi < 4; ++mi)
#pragma unroll
                for (int ni = 0; ni < 2; ++ni)
                    acc[mi][ni] = __builtin_amdgcn_mfma_f32_16x16x32_bf16(
                        af[mi], bfr[ni], acc[mi][ni], 0, 0, 0);
        }
    }

    if (seg < 2) {
        ushort_t* C = seg == 0 ? qbb : kbb;
#pragma unroll
        for (int mi = 0; mi < 4; ++mi)
#pragma unroll
            for (int ni = 0; ni < 2; ++ni) {
                int gn = nloc + wc * 32 + ni * 16 + l15;
                float bv = bias[gn];
#pragma unroll
                for (int r = 0; r < 4; ++r) {
                    int gm = m0 + wr * 64 + mi * 16 + quad * 4 + r;
                    C[(size_t)gm * DMOD + gn] = f2b(acc[mi][ni][r] + bv);
                }
            }
    } else {
#pragma unroll
        for (int mi = 0; mi < 4; ++mi)
#pragma unroll
            for (int ni = 0; ni < 2; ++ni) {
                int gn = nloc + wc * 32 + ni * 16 + l15;   // v_global
                float bv = bias[gn];
                int gmb = m0 + wr * 64 + mi * 16 + quad * 4;
                union { uint2 u2; ushort_t us[4]; } o;
#pragma unroll
                for (int r = 0; r < 4; ++r) o.us[r] = f2b(acc[mi][ni][r] + bv);
                *(uint2*)&vt[(size_t)gn * S + gmb] = o.u2;
            }
    }
}

// ---------------------------------------------------------------------------
// Attention core. Block = (s-tile 64, t-half, head). Double-buffered K/V via
// async global->LDS prefetched one step ahead; ONE barrier per step; Ps is
// wave-private (no barrier). Output accumulated with fp32 atomics.
// ---------------------------------------------------------------------------
__global__ __launch_bounds__(256) void attn_mfma(
    const ushort_t* __restrict__ qb, const ushort_t* __restrict__ kb,
    const ushort_t* __restrict__ vt, float* __restrict__ attn_raw,
    float* __restrict__ sumexp)
{
    __shared__ ushort_t Qs[4096];
    __shared__ ushort_t Ks[2][4096];
    __shared__ ushort_t Vs[2][4096];   // [v][t] tiles (V pre-transposed globally)
    __shared__ ushort_t Ps[4096];      // [s][t], wave-private row bands

    const int h = blockIdx.y;
    const int bx = blockIdx.x;
    const int si = 31 - (bx >> 1);     // long blocks dispatch first
    const int z = bx & 1;
    const int nt = si + 1;
    const int half0 = (nt + 1) >> 1;
    const int tbeg = z ? half0 : 0;
    const int tend = z ? nt : half0;
    if (tbeg >= tend) return;
    const int s0 = si * 64;

    const int tid = threadIdx.x;
    const int lane = tid & 63, w = tid >> 6;
    const int quad = lane >> 4, l15 = lane & 15;

    const ushort_t* qh = qb + h * 64;
    const ushort_t* kh = kb + h * 64;
    const ushort_t* vh = vt + (size_t)(h * 64) * S;

    // stage Q once + first K/V into buf 0
#pragma unroll
    for (int i = 0; i < 2; ++i) {
        int c = i * 256 + tid, row = c >> 3, kcl = c & 7;
        gld16(qh + (size_t)(s0 + row) * DMOD + (kcl ^ SW(row)) * 8, &Qs[c * 8]);
    }
    {
        int t0 = tbeg * 64;
#pragma unroll
        for (int i = 0; i < 2; ++i) {
            int c = i * 256 + tid, row = c >> 3, kcl = c & 7;
            gld16(kh + (size_t)(t0 + row) * DMOD + (kcl ^ SW(row)) * 8, &Ks[0][c * 8]);
            gld16(vh + (size_t)row * S + t0 + (kcl ^ SW(row)) * 8, &Vs[0][c * 8]);
        }
    }
    __syncthreads();

    const f32x4 fz = {0.f, 0.f, 0.f, 0.f};
    f32x4 oacc[4];
#pragma unroll
    for (int ni = 0; ni < 4; ++ni) oacc[ni] = fz;

    for (int it = tbeg; it < tend; ++it) {
        const int p = (it - tbeg) & 1;
        const int t0 = it * 64;
        // prefetch next K/V into the other buffer (lands by next barrier)
        if (it + 1 < tend) {
            int t1 = t0 + 64;
#pragma unroll
            for (int i = 0; i < 2; ++i) {
                int c = i * 256 + tid, row = c >> 3, kcl = c & 7;
                gld16(kh + (size_t)(t1 + row) * DMOD + (kcl ^ SW(row)) * 8, &Ks[1 - p][c * 8]);
                gld16(vh + (size_t)row * S + t1 + (kcl ^ SW(row)) * 8, &Vs[1 - p][c * 8]);
            }
        }

        // X = Q K^T
        f32x4 xf[4];
#pragma unroll
        for (int ti = 0; ti < 4; ++ti) xf[ti] = fz;
#pragma unroll
        for (int kc = 0; kc < 2; ++kc) {
            int rq = w * 16 + l15;
            bf16x8 aq = *(const bf16x8*)&Qs[rq * 64 + ((kc * 4 + quad) ^ SW(rq)) * 8];
#pragma unroll
            for (int ti = 0; ti < 4; ++ti) {
                int rk = ti * 16 + l15;
                bf16x8 bk = *(const bf16x8*)&Ks[p][rk * 64 + ((kc * 4 + quad) ^ SW(rk)) * 8];
                xf[ti] = __builtin_amdgcn_mfma_f32_16x16x32_bf16(aq, bk, xf[ti], 0, 0, 0);
            }
        }

        // scale, mask, exp column sums (global atomic), P -> wave-private LDS
        const int s_base = s0 + w * 16 + quad * 4;
        const bool diag = (t0 == s0);
#pragma unroll
        for (int ti = 0; ti < 4; ++ti) {
            int t_g = t0 + ti * 16 + l15;
            float es = 0.f;
#pragma unroll
            for (int r = 0; r < 4; ++r) {
                float xv = xf[ti][r] * 0.125f;
                bool live = (!diag) || (s_base + r >= t_g);
                xv = live ? xv : 0.f;
                es += live ? __expf(xv) : 0.f;
                xf[ti][r] = xv;
            }
            es += __shfl_xor(es, 16, 64);
            es += __shfl_xor(es, 32, 64);
            if (quad == 0) atomicAdd(&sumexp[h * S + t_g], es);
#pragma unroll
            for (int r = 0; r < 4; ++r) {
                int sl = w * 16 + quad * 4 + r;
                int tc = ti * 16 + l15;
                Ps[sl * 64 + ((tc >> 3) ^ SW(sl)) * 8 + (tc & 7)] = f2b(xf[ti][r]);
            }
        }

        // O += P V   (reads only this wave's Ps rows; per-wave lgkm ordering)
#pragma unroll
        for (int kc = 0; kc < 2; ++kc) {
            int rp = w * 16 + l15;
            bf16x8 ap = *(const bf16x8*)&Ps[rp * 64 + ((kc * 4 + quad) ^ SW(rp)) * 8];
#pragma unroll
            for (int ni = 0; ni < 4; ++ni) {
                int rv = ni * 16 + l15;
                bf16x8 bv = *(const bf16x8*)&Vs[p][rv * 64 + ((kc * 4 + quad) ^ SW(rv)) * 8];
                oacc[ni] = __builtin_amdgcn_mfma_f32_16x16x32_bf16(ap, bv, oacc[ni], 0, 0, 0);
            }
        }
        __syncthreads();   // all waves done with buf p; next iter stages into it
    }

#pragma unroll
    for (int ni = 0; ni < 4; ++ni)
#pragma unroll
        for (int r = 0; r < 4; ++r) {
            int s_g = s0 + w * 16 + quad * 4 + r;
            atomicAdd(&attn_raw[(size_t)s_g * DMOD + h * 64 + ni * 16 + l15],
                      oacc[ni][r]);
        }
}

// ---------------------------------------------------------------------------
__global__ void lse_kernel(float* __restrict__ sumexp) {
    int i = blockIdx.x * blockDim.x + threadIdx.x;
    if (i < H * S) sumexp[i] = logf(sumexp[i]);
}

// ---------------------------------------------------------------------------
// corr[r=h*64+j] = sum_t lse[h,t] * vt[r][t]; one wave per row.
// ---------------------------------------------------------------------------
__global__ __launch_bounds__(256) void corr_kernel(
    const float* __restrict__ lse, const ushort_t* __restrict__ vt,
    float* __restrict__ corr)
{
    const int w = threadIdx.x >> 6, lane = threadIdx.x & 63;
    const int r = blockIdx.x * 4 + w;       // 0..1023
    const int h = r >> 6;
    float acc = 0.f;
#pragma unroll
    for (int i = 0; i < 4; ++i) {
        int t = i * 512 + lane * 8;
        bf16x8 vv = *(const bf16x8*)&vt[(size_t)r * S + t];
        float4 l0 = *(const float4*)&lse[h * S + t];
        float4 l1 = *(const float4*)&lse[h * S + t + 4];
        acc += l0.x * b2f((ushort_t)vv[0]) + l0.y * b2f((ushort_t)vv[1])
             + l0.z * b2f((ushort_t)vv[2]) + l0.w * b2f((ushort_t)vv[3])
             + l1.x * b2f((ushort_t)vv[4]) + l1.y * b2f((ushort_t)vv[5])
             + l1.z * b2f((ushort_t)vv[6]) + l1.w * b2f((ushort_t)vv[7]);
    }
#pragma unroll
    for (int d = 1; d < 64; d <<= 1) acc += __shfl_xor(acc, d, 64);
    if (lane == 0) corr[r] = acc;
}

// ---------------------------------------------------------------------------
__global__ __launch_bounds__(256) void convert_Z(
    const float* __restrict__ attn_raw, const float* __restrict__ corr,
    ushort_t* __restrict__ Zb)
{
    size_t i = ((size_t)blockIdx.x * 256 + threadIdx.x) * 4;
    float4 f = *(const float4*)(attn_raw + i);
    int c = (int)(i & (DMOD - 1));
    union { uint2 u2; ushort_t us[4]; } o;
    o.us[0] = f2b(f.x - corr[c]);
    o.us[1] = f2b(f.y - corr[c + 1]);
    o.us[2] = f2b(f.z - corr[c + 2]);
    o.us[3] = f2b(f.w - corr[c + 3]);
    *(uint2*)(Zb + i) = o.u2;
}

// ---------------------------------------------------------------------------
// Output GEMM, split-K=2, atomic fp32 epilogue (d_out zeroed beforehand).
// ---------------------------------------------------------------------------
__global__ __launch_bounds__(256) void gemm_out(
    const ushort_t* __restrict__ A, const ushort_t* __restrict__ W,
    const float* __restrict__ bias, float* __restrict__ C)
{
    __shared__ ushort_t As[128 * 64];
    __shared__ ushort_t Bs[64 * 64];
    const int tid = threadIdx.x;
    const int lane = tid & 63, wid = tid >> 6;
    const int quad = lane >> 4, l15 = lane & 15;
    const int wr = wid >> 1, wc = wid & 1;
    const int m0 = blockIdx.y * 128, n0 = blockIdx.x * 64;
    const int kbeg = blockIdx.z * 512, kend = kbeg + 512;

    const f32x4 fz = {0.f, 0.f, 0.f, 0.f};
    f32x4 acc[4][2];
#pragma unroll
    for (int i = 0; i < 4; ++i) { acc[i][0] = fz; acc[i][1] = fz; }

    for (int k0 = kbeg; k0 < kend; k0 += 64) {
        __syncthreads();
#pragma unroll
        for (int i = 0; i < 4; ++i) {
            int c = i * 256 + tid, row = c >> 3, kcl = c & 7;
            gld16(A + (size_t)(m0 + row) * DMOD + k0 + (kcl ^ SW(row)) * 8, &As[c * 8]);
        }
#pragma unroll
        for (int i = 0; i < 2; ++i) {
            int c = i * 256 + tid, row = c >> 3, kcl = c & 7;
            gld16(W + (size_t)(n0 + row) * DMOD + k0 + (kcl ^ SW(row)) * 8, &Bs[c * 8]);
        }
        __syncthreads();
#pragma unroll
        for (int kc = 0; kc < 2; ++kc) {
            bf16x8 af[4], bfr[2];
#pragma unroll
            for (int mi = 0; mi < 4; ++mi) {
                int row = wr * 64 + mi * 16 + l15;
                af[mi] = *(const bf16x8*)&As[row * 64 + ((kc * 4 + quad) ^ SW(row)) * 8];
            }
#pragma unroll
            for (int ni = 0; ni < 2; ++ni) {
                int row = wc * 32 + ni * 16 + l15;
                bfr[ni] = *(const bf16x8*)&Bs[row * 64 + ((kc * 4 + quad) ^ SW(row)) * 8];
            }
#pragma unroll
            for (int mi = 0; mi < 4; ++mi)
#pragma unroll
                for (int ni = 0; ni < 2; ++ni)
                    acc[mi][ni] = __builtin_amdgcn_mfma_f32_16x16x32_bf16(
                        af[mi], bfr[ni], acc[mi][ni], 0, 0, 0);
        }
    }
#pragma unroll
    for (int mi = 0; mi < 4; ++mi)
#pragma unroll
        for (int ni = 0; ni < 2; ++ni) {
            int gn = n0 + wc * 32 + ni * 16 + l15;
            float bv = (kbeg == 0) ? bias[gn] : 0.f;
#pragma unroll
            for (int r = 0; r < 4; ++r) {
                int gm = m0 + wr * 64 + mi * 16 + quad * 4 + r;
                atomicAdd(&C[(size_t)gm * DMOD + gn], acc[mi][ni][r] + bv);
            }
        }
}

// ---------------------------------------------------------------------------
extern "C" void kernel_launch(void* const* d_in, const int* in_sizes, int n_in,
                              void* d_out, int out_size, void* d_ws, size_t ws_size,
                              hipStream_t stream) {
    const float* Qin = (const float*)d_in[0];
    const float* Kin = (const float*)d_in[1];
    const float* Vin = (const float*)d_in[2];
    const float* WQw = (const float*)d_in[3];
    const float* WQb = (const float*)d_in[4];
    const float* WKw = (const float*)d_in[5];
    const float* WKb = (const float*)d_in[6];
    const float* WVw = (const float*)d_in[7];
    const float* WVb = (const float*)d_in[8];
    const float* WOw = (const float*)d_in[9];
    const float* WOb = (const float*)d_in[10];

    float* ws = (float*)d_ws;
    const size_t M1 = (size_t)1 << 20;
    ushort_t* qbb  = (ushort_t*)(ws);                 // [2048][1024] bf16
    ushort_t* kbb  = (ushort_t*)(ws + M1);
    ushort_t* vt   = (ushort_t*)(ws + 2 * M1);        // [1024 v][2048 t] bf16
    ushort_t* wqkv = (ushort_t*)(ws + 3 * M1);        // [3072][1024] bf16
    ushort_t* wob  = (ushort_t*)(ws + 4 * M1 + M1 / 2);
    ushort_t* Qbin = (ushort_t*)(ws + 5 * M1);        // reused as Zb
    ushort_t* Kbin = (ushort_t*)(ws + 6 * M1);        // \ reused as
    ushort_t* Vbin = (ushort_t*)(ws + 7 * M1);        // / attn_raw (2M fl)
    float* attn_raw = ws + 6 * M1;
    ushort_t* Zb    = (ushort_t*)(ws + 5 * M1);
    float* sumexp   = ws + 8 * M1;                    // 32768
    float* corr     = ws + 8 * M1 + H * S;            // 1024

    init_sumexp<<<(H * S + H * 64 + 255) / 256, 256, 0, stream>>>(sumexp);
    hipMemsetAsync(attn_raw, 0, (size_t)S * DMOD * sizeof(float), stream);
    hipMemsetAsync(d_out, 0, (size_t)S * DMOD * sizeof(float), stream);

    convert_all<<<dim3(1024, 10), 256, 0, stream>>>(
        Qin, Kin, Vin, WQw, WKw, WVw, WOw,
        Qbin, Kbin, Vbin,
        wqkv, wqkv + (size_t)1024 * 1024, wqkv + (size_t)2 * 1024 * 1024, wob);

    gemm_qkv<<<dim3(48, 16), 256, 0, stream>>>(
        Qbin, Kbin, Vbin, wqkv, WQb, WKb, WVb, qbb, kbb, vt);

    attn_mfma<<<dim3(64, H), 256, 0, stream>>>(qbb, kbb, vt, attn_raw, sumexp);

    lse_kernel<<<128, 256, 0, stream>>>(sumexp);
    corr_kernel<<<256, 256, 0, stream>>>(sumexp, vt, corr);
    convert_Z<<<2048, 256, 0, stream>>>(attn_raw, corr, Zb);

    gemm_out<<<dim3(16, 16, 2), 256, 0, stream>>>(Zb, wob, WOb, (float*)d_out);
}

// Round 5
// 204.703 us; speedup vs baseline: 8.5640x; 1.0467x over previous
//
#include <hip/hip_runtime.h>
#include <math.h>
#include <stdint.h>

#define S 2048
#define DMOD 1024
#define H 16

typedef unsigned short ushort_t;
typedef short bf16x8 __attribute__((ext_vector_type(8)));
typedef float f32x4 __attribute__((ext_vector_type(4)));

// chunk swizzle: rows 1..7 apart and 8 apart land on different chunk columns
#define SW(r) ((((r) & 7)) ^ ((((r) >> 3) & 3) << 1))

__device__ __forceinline__ ushort_t f2b(float f) {
    union { float f; unsigned u; } x; x.f = f;
    return (ushort_t)((x.u + 0x7FFFu + ((x.u >> 16) & 1u)) >> 16);
}
__device__ __forceinline__ float b2f(ushort_t b) {
    union { unsigned u; float f; } x; x.u = ((unsigned)b) << 16;
    return x.f;
}
__device__ __forceinline__ void gld16(const ushort_t* g, ushort_t* l) {
    __builtin_amdgcn_global_load_lds(
        (const __attribute__((address_space(1))) unsigned int*)g,
        (__attribute__((address_space(3))) unsigned int*)l, 16, 0, 0);
}

// ---------------------------------------------------------------------------
// One init kernel: zero attn_raw (2M fl), zero d_out (2M fl), init sumexp=t,
// zero corr. Grid 4129 x 256.
// ---------------------------------------------------------------------------
__global__ __launch_bounds__(256) void init_all(
    float* __restrict__ attn_raw, float* __restrict__ out,
    float* __restrict__ sumexp, float* __restrict__ corr)
{
    const int b = blockIdx.x;
    const float4 z4 = {0.f, 0.f, 0.f, 0.f};
    if (b < 2048) {
        *(float4*)(attn_raw + ((size_t)b * 256 + threadIdx.x) * 4) = z4;
    } else if (b < 4096) {
        *(float4*)(out + ((size_t)(b - 2048) * 256 + threadIdx.x) * 4) = z4;
    } else if (b < 4128) {
        int e = ((b - 4096) * 256 + threadIdx.x) * 4;
        float4 v = {(float)(e & 2047), (float)((e + 1) & 2047),
                    (float)((e + 2) & 2047), (float)((e + 3) & 2047)};
        *(float4*)(sumexp + e) = v;
    } else {
        *(float4*)(corr + threadIdx.x * 4) = z4;
    }
}

// ---------------------------------------------------------------------------
__global__ __launch_bounds__(256) void convert_all(
    const float* q, const float* k, const float* v,
    const float* wq, const float* wk, const float* wv, const float* wo,
    ushort_t* qo, ushort_t* ko, ushort_t* vo,
    ushort_t* wqo, ushort_t* wko, ushort_t* wvo, ushort_t* woo)
{
    const int seg = blockIdx.y;
    const float* src; ushort_t* dst; size_t off = 0;
    const size_t M1 = (size_t)1 << 20;
    if (seg < 2)       { src = q;  dst = qo;  off = (size_t)seg * M1; }
    else if (seg < 4)  { src = k;  dst = ko;  off = (size_t)(seg - 2) * M1; }
    else if (seg < 6)  { src = v;  dst = vo;  off = (size_t)(seg - 4) * M1; }
    else if (seg == 6) { src = wq; dst = wqo; }
    else if (seg == 7) { src = wk; dst = wko; }
    else if (seg == 8) { src = wv; dst = wvo; }
    else               { src = wo; dst = woo; }
    size_t i = off + ((size_t)blockIdx.x * 256 + threadIdx.x) * 4;
    float4 f = *(const float4*)(src + i);
    union { uint2 u2; ushort_t us[4]; } o;
    o.us[0] = f2b(f.x); o.us[1] = f2b(f.y); o.us[2] = f2b(f.z); o.us[3] = f2b(f.w);
    *(uint2*)(dst + i) = o.u2;
}

// ---------------------------------------------------------------------------
// Fused QKV projection GEMM: block tile 128x64 over N=3072 (Q|K|V).
// seg 0/1 -> bf16 store to qbb/kbb [t][1024]; seg 2 -> transposed store to
// vt [v_global 1024][t 2048].
// ---------------------------------------------------------------------------
__global__ __launch_bounds__(256) void gemm_qkv(
    const ushort_t* __restrict__ A0, const ushort_t* __restrict__ A1,
    const ushort_t* __restrict__ A2, const ushort_t* __restrict__ Wqkv,
    const float* __restrict__ b0, const float* __restrict__ b1,
    const float* __restrict__ b2,
    ushort_t* __restrict__ qbb, ushort_t* __restrict__ kbb,
    ushort_t* __restrict__ vt)
{
    __shared__ ushort_t As[128 * 64];
    __shared__ ushort_t Bs[64 * 64];
    const int tid = threadIdx.x;
    const int lane = tid & 63, wid = tid >> 6;
    const int quad = lane >> 4, l15 = lane & 15;
    const int wr = wid >> 1, wc = wid & 1;
    const int m0 = blockIdx.y * 128;
    const int n0 = blockIdx.x * 64;
    const int seg = n0 >> 10;
    const int nloc = n0 & 1023;
    const ushort_t* A = seg == 0 ? A0 : (seg == 1 ? A1 : A2);
    const float* bias = seg == 0 ? b0 : (seg == 1 ? b1 : b2);

    const f32x4 fz = {0.f, 0.f, 0.f, 0.f};
    f32x4 acc[4][2];
#pragma unroll
    for (int i = 0; i < 4; ++i) { acc[i][0] = fz; acc[i][1] = fz; }

    for (int k0 = 0; k0 < DMOD; k0 += 64) {
        __syncthreads();
#pragma unroll
        for (int i = 0; i < 4; ++i) {
            int c = i * 256 + tid, row = c >> 3, kcl = c & 7;
            gld16(A + (size_t)(m0 + row) * DMOD + k0 + (kcl ^ SW(row)) * 8, &As[c * 8]);
        }
#pragma unroll
        for (int i = 0; i < 2; ++i) {
            int c = i * 256 + tid, row = c >> 3, kcl = c & 7;
            gld16(Wqkv + (size_t)(n0 + row) * DMOD + k0 + (kcl ^ SW(row)) * 8, &Bs[c * 8]);
        }
        __syncthreads();
#pragma unroll
        for (int kc = 0; kc < 2; ++kc) {
            bf16x8 af[4], bfr[2];
#pragma unroll
            for (int mi = 0; mi < 4; ++mi) {
                int row = wr * 64 + mi * 16 + l15;
                af[mi] = *(const bf16x8*)&As[row * 64 + ((kc * 4 + quad) ^ SW(row)) * 8];
            }
#pragma unroll
            for (int ni = 0; ni < 2; ++ni) {
                int row = wc * 32 + ni * 16 + l15;
                bfr[ni] = *(const bf16x8*)&Bs[row * 64 + ((kc * 4 + quad) ^ SW(row)) * 8];
            }
#pragma unroll
            for (int mi = 0; mi < 4; ++mi)
#pragma unroll
                for (int ni = 0; ni < 2; ++ni)
                    acc[mi][ni] = __builtin_amdgcn_mfma_f32_16x16x32_bf16(
                        af[mi], bfr[ni], acc[mi][ni], 0, 0, 0);
        }
    }

    if (seg < 2) {
        ushort_t* C = seg == 0 ? qbb : kbb;
#pragma unroll
        for (int mi = 0; mi < 4; ++mi)
#pragma unroll
            for (int ni = 0; ni < 2; ++ni) {
                int gn = nloc + wc * 32 + ni * 16 + l15;
                float bv = bias[gn];
#pragma unroll
                for (int r = 0; r < 4; ++r) {
                    int gm = m0 + wr * 64 + mi * 16 + quad * 4 + r;
                    C[(size_t)gm * DMOD + gn] = f2b(acc[mi][ni][r] + bv);
                }
            }
    } else {
#pragma unroll
        for (int mi = 0; mi < 4; ++mi)
#pragma unroll
            for (int ni = 0; ni < 2; ++ni) {
                int gn = nloc + wc * 32 + ni * 16 + l15;   // v_global
                float bv = bias[gn];
                int gmb = m0 + wr * 64 + mi * 16 + quad * 4;
                union { uint2 u2; ushort_t us[4]; } o;
#pragma unroll
                for (int r = 0; r < 4; ++r) o.us[r] = f2b(acc[mi][ni][r] + bv);
                *(uint2*)&vt[(size_t)gn * S + gmb] = o.u2;
            }
    }
}

// ---------------------------------------------------------------------------
// Attention core v3. Block = (s-tile 128, t-half, head): 512 threads, 8 waves,
// each wave owns a 16-row band. Double-buffered K/V prefetch one step ahead;
// one barrier per step; Ps wave-private; exp sums accumulated in LDS (ds_add)
// with a single global atomic burst at the end. Fully-masked bands skip.
// ---------------------------------------------------------------------------
__global__ __launch_bounds__(512, 4) void attn_mfma(
    const ushort_t* __restrict__ qb, const ushort_t* __restrict__ kb,
    const ushort_t* __restrict__ vt, float* __restrict__ attn_raw,
    float* __restrict__ sumexp)
{
    __shared__ ushort_t Qs[128 * 64];
    __shared__ ushort_t Ks[2][4096];
    __shared__ ushort_t Vs[2][4096];
    __shared__ ushort_t Ps[128 * 64];
    __shared__ float    sacc[1024];

    const int h = blockIdx.y;
    const int bx = blockIdx.x;
    const int si = 15 - (bx >> 1);     // long blocks dispatch first
    const int z = bx & 1;
    const int half = si + 1;           // steps per z-block (balanced)
    const int tbeg = z ? half : 0;
    const int tend = z ? 2 * si + 2 : half;
    const int s0 = si * 128;

    const int tid = threadIdx.x;
    const int lane = tid & 63, w = tid >> 6;
    const int quad = lane >> 4, l15 = lane & 15;
    const int sband = s0 + w * 16;     // wave's lowest s row

    const ushort_t* qh = qb + h * 64;
    const ushort_t* kh = kb + h * 64;
    const ushort_t* vh = vt + (size_t)(h * 64) * S;

    // stage Q (128x64) + first K/V into buf 0
#pragma unroll
    for (int i = 0; i < 2; ++i) {
        int c = i * 512 + tid, row = c >> 3, kcl = c & 7;
        gld16(qh + (size_t)(s0 + row) * DMOD + (kcl ^ SW(row)) * 8, &Qs[c * 8]);
    }
    {
        int t0 = tbeg * 64;
        int row = tid >> 3, kcl = tid & 7;
        gld16(kh + (size_t)(t0 + row) * DMOD + (kcl ^ SW(row)) * 8, &Ks[0][tid * 8]);
        gld16(vh + (size_t)row * S + t0 + (kcl ^ SW(row)) * 8, &Vs[0][tid * 8]);
    }
    for (int i = tid; i < 1024; i += 512) sacc[i] = 0.f;
    __syncthreads();

    // hoist step-invariant Q fragments
    bf16x8 aq[2];
    {
        int rq = w * 16 + l15;
#pragma unroll
        for (int kc = 0; kc < 2; ++kc)
            aq[kc] = *(const bf16x8*)&Qs[rq * 64 + ((kc * 4 + quad) ^ SW(rq)) * 8];
    }

    const f32x4 fz = {0.f, 0.f, 0.f, 0.f};
    f32x4 oacc[4];
#pragma unroll
    for (int ni = 0; ni < 4; ++ni) oacc[ni] = fz;

    for (int it = tbeg; it < tend; ++it) {
        const int p = (it - tbeg) & 1;
        const int t0 = it * 64;
        // prefetch next K/V into the other buffer (overlaps this step's compute)
        if (it + 1 < tend) {
            int t1 = t0 + 64;
            int row = tid >> 3, kcl = tid & 7;
            gld16(kh + (size_t)(t1 + row) * DMOD + (kcl ^ SW(row)) * 8, &Ks[1 - p][tid * 8]);
            gld16(vh + (size_t)row * S + t1 + (kcl ^ SW(row)) * 8, &Vs[1 - p][tid * 8]);
        }

        if (t0 < sband + 16) {   // not fully masked for this wave band
            // X = Q K^T
            f32x4 xf[4];
#pragma unroll
            for (int ti = 0; ti < 4; ++ti) xf[ti] = fz;
#pragma unroll
            for (int kc = 0; kc < 2; ++kc) {
#pragma unroll
                for (int ti = 0; ti < 4; ++ti) {
                    int rk = ti * 16 + l15;
                    bf16x8 bk = *(const bf16x8*)&Ks[p][rk * 64 + ((kc * 4 + quad) ^ SW(rk)) * 8];
                    xf[ti] = __builtin_amdgcn_mfma_f32_16x16x32_bf16(aq[kc], bk, xf[ti], 0, 0, 0);
                }
            }

            // scale, mask, exp column sums -> LDS, P -> wave-private LDS
            const bool clean = (t0 + 63 <= sband);   // no masking possible
            const int s_q = sband + quad * 4;
#pragma unroll
            for (int ti = 0; ti < 4; ++ti) {
                int t_g = t0 + ti * 16 + l15;
                float es = 0.f;
#pragma unroll
                for (int r = 0; r < 4; ++r) {
                    float xv = xf[ti][r] * 0.125f;
                    bool live = clean || (s_q + r >= t_g);
                    xv = live ? xv : 0.f;
                    es += live ? __expf(xv) : 0.f;
                    xf[ti][r] = xv;
                }
                es += __shfl_xor(es, 16, 64);
                es += __shfl_xor(es, 32, 64);
                if (quad == 0) atomicAdd(&sacc[t0 - tbeg * 64 + ti * 16 + l15], es);
#pragma unroll
                for (int r = 0; r < 4; ++r) {
                    int sl = w * 16 + quad * 4 + r;
                    int tc = ti * 16 + l15;
                    Ps[sl * 64 + ((tc >> 3) ^ SW(sl)) * 8 + (tc & 7)] = f2b(xf[ti][r]);
                }
            }

            // O += P V   (reads only this wave's Ps rows)
#pragma unroll
            for (int kc = 0; kc < 2; ++kc) {
                int rp = w * 16 + l15;
                bf16x8 ap = *(const bf16x8*)&Ps[rp * 64 + ((kc * 4 + quad) ^ SW(rp)) * 8];
#pragma unroll
                for (int ni = 0; ni < 4; ++ni) {
                    int rv = ni * 16 + l15;
                    bf16x8 bv = *(const bf16x8*)&Vs[p][rv * 64 + ((kc * 4 + quad) ^ SW(rv)) * 8];
                    oacc[ni] = __builtin_amdgcn_mfma_f32_16x16x32_bf16(ap, bv, oacc[ni], 0, 0, 0);
                }
            }
        }
        __syncthreads();   // all waves done with buf p; next iter stages into it
    }

    // exp-sum burst: one global atomic per covered t
    {
        int nv = (tend - tbeg) * 64;
        for (int i = tid; i < nv; i += 512)
            atomicAdd(&sumexp[h * S + tbeg * 64 + i], sacc[i]);
    }
    // O accumulate (two z-blocks per (h,si) sum into zeroed attn_raw)
#pragma unroll
    for (int ni = 0; ni < 4; ++ni)
#pragma unroll
        for (int r = 0; r < 4; ++r) {
            int s_g = s0 + w * 16 + quad * 4 + r;
            atomicAdd(&attn_raw[(size_t)s_g * DMOD + h * 64 + ni * 16 + l15],
                      oacc[ni][r]);
        }
}

// ---------------------------------------------------------------------------
// corr[r=h*64+j] = sum_t log(sumexp[h,t]) * vt[r][t]; one wave per row.
// ---------------------------------------------------------------------------
__global__ __launch_bounds__(256) void corr_kernel(
    const float* __restrict__ sumexp, const ushort_t* __restrict__ vt,
    float* __restrict__ corr)
{
    const int w = threadIdx.x >> 6, lane = threadIdx.x & 63;
    const int r = blockIdx.x * 4 + w;       // 0..1023
    const int h = r >> 6;
    float acc = 0.f;
#pragma unroll
    for (int i = 0; i < 4; ++i) {
        int t = i * 512 + lane * 8;
        bf16x8 vv = *(const bf16x8*)&vt[(size_t)r * S + t];
        float4 s0 = *(const float4*)&sumexp[h * S + t];
        float4 s1 = *(const float4*)&sumexp[h * S + t + 4];
        acc += logf(s0.x) * b2f((ushort_t)vv[0]) + logf(s0.y) * b2f((ushort_t)vv[1])
             + logf(s0.z) * b2f((ushort_t)vv[2]) + logf(s0.w) * b2f((ushort_t)vv[3])
             + logf(s1.x) * b2f((ushort_t)vv[4]) + logf(s1.y) * b2f((ushort_t)vv[5])
             + logf(s1.z) * b2f((ushort_t)vv[6]) + logf(s1.w) * b2f((ushort_t)vv[7]);
    }
#pragma unroll
    for (int d = 1; d < 64; d <<= 1) acc += __shfl_xor(acc, d, 64);
    if (lane == 0) corr[r] = acc;
}

// ---------------------------------------------------------------------------
__global__ __launch_bounds__(256) void convert_Z(
    const float* __restrict__ attn_raw, const float* __restrict__ corr,
    ushort_t* __restrict__ Zb)
{
    size_t i = ((size_t)blockIdx.x * 256 + threadIdx.x) * 4;
    float4 f = *(const float4*)(attn_raw + i);
    int c = (int)(i & (DMOD - 1));
    union { uint2 u2; ushort_t us[4]; } o;
    o.us[0] = f2b(f.x - corr[c]);
    o.us[1] = f2b(f.y - corr[c + 1]);
    o.us[2] = f2b(f.z - corr[c + 2]);
    o.us[3] = f2b(f.w - corr[c + 3]);
    *(uint2*)(Zb + i) = o.u2;
}

// ---------------------------------------------------------------------------
// Output GEMM, split-K=2, atomic fp32 epilogue (d_out zeroed by init_all).
// ---------------------------------------------------------------------------
__global__ __launch_bounds__(256) void gemm_out(
    const ushort_t* __restrict__ A, const ushort_t* __restrict__ W,
    const float* __restrict__ bias, float* __restrict__ C)
{
    __shared__ ushort_t As[128 * 64];
    __shared__ ushort_t Bs[64 * 64];
    const int tid = threadIdx.x;
    const int lane = tid & 63, wid = tid >> 6;
    const int quad = lane >> 4, l15 = lane & 15;
    const int wr = wid >> 1, wc = wid & 1;
    const int m0 = blockIdx.y * 128, n0 = blockIdx.x * 64;
    const int kbeg = blockIdx.z * 512, kend = kbeg + 512;

    const f32x4 fz = {0.f, 0.f, 0.f, 0.f};
    f32x4 acc[4][2];
#pragma unroll
    for (int i = 0; i < 4; ++i) { acc[i][0] = fz; acc[i][1] = fz; }

    for (int k0 = kbeg; k0 < kend; k0 += 64) {
        __syncthreads();
#pragma unroll
        for (int i = 0; i < 4; ++i) {
            int c = i * 256 + tid, row = c >> 3, kcl = c & 7;
            gld16(A + (size_t)(m0 + row) * DMOD + k0 + (kcl ^ SW(row)) * 8, &As[c * 8]);
        }
#pragma unroll
        for (int i = 0; i < 2; ++i) {
            int c = i * 256 + tid, row = c >> 3, kcl = c & 7;
            gld16(W + (size_t)(n0 + row) * DMOD + k0 + (kcl ^ SW(row)) * 8, &Bs[c * 8]);
        }
        __syncthreads();
#pragma unroll
        for (int kc = 0; kc < 2; ++kc) {
            bf16x8 af[4], bfr[2];
#pragma unroll
            for (int mi = 0; mi < 4; ++mi) {
                int row = wr * 64 + mi * 16 + l15;
                af[mi] = *(const bf16x8*)&As[row * 64 + ((kc * 4 + quad) ^ SW(row)) * 8];
            }
#pragma unroll
            for (int ni = 0; ni < 2; ++ni) {
                int row = wc * 32 + ni * 16 + l15;
                bfr[ni] = *(const bf16x8*)&Bs[row * 64 + ((kc * 4 + quad) ^ SW(row)) * 8];
            }
#pragma unroll
            for (int mi = 0; mi < 4; ++mi)
#pragma unroll
                for (int ni = 0; ni < 2; ++ni)
                    acc[mi][ni] = __builtin_amdgcn_mfma_f32_16x16x32_bf16(
                        af[mi], bfr[ni], acc[mi][ni], 0, 0, 0);
        }
    }
#pragma unroll
    for (int mi = 0; mi < 4; ++mi)
#pragma unroll
        for (int ni = 0; ni < 2; ++ni) {
            int gn = n0 + wc * 32 + ni * 16 + l15;
            float bv = (kbeg == 0) ? bias[gn] : 0.f;
#pragma unroll
            for (int r = 0; r < 4; ++r) {
                int gm = m0 + wr * 64 + mi * 16 + quad * 4 + r;
                atomicAdd(&C[(size_t)gm * DMOD + gn], acc[mi][ni][r] + bv);
            }
        }
}

// ---------------------------------------------------------------------------
extern "C" void kernel_launch(void* const* d_in, const int* in_sizes, int n_in,
                              void* d_out, int out_size, void* d_ws, size_t ws_size,
                              hipStream_t stream) {
    const float* Qin = (const float*)d_in[0];
    const float* Kin = (const float*)d_in[1];
    const float* Vin = (const float*)d_in[2];
    const float* WQw = (const float*)d_in[3];
    const float* WQb = (const float*)d_in[4];
    const float* WKw = (const float*)d_in[5];
    const float* WKb = (const float*)d_in[6];
    const float* WVw = (const float*)d_in[7];
    const float* WVb = (const float*)d_in[8];
    const float* WOw = (const float*)d_in[9];
    const float* WOb = (const float*)d_in[10];

    float* ws = (float*)d_ws;
    const size_t M1 = (size_t)1 << 20;
    ushort_t* qbb  = (ushort_t*)(ws);                 // [2048][1024] bf16
    ushort_t* kbb  = (ushort_t*)(ws + M1);
    ushort_t* vt   = (ushort_t*)(ws + 2 * M1);        // [1024 v][2048 t] bf16
    ushort_t* wqkv = (ushort_t*)(ws + 3 * M1);        // [3072][1024] bf16
    ushort_t* wob  = (ushort_t*)(ws + 4 * M1 + M1 / 2);
    ushort_t* Qbin = (ushort_t*)(ws + 5 * M1);        // reused as Zb
    ushort_t* Kbin = (ushort_t*)(ws + 6 * M1);        // \ reused as
    ushort_t* Vbin = (ushort_t*)(ws + 7 * M1);        // / attn_raw (2M fl)
    float* attn_raw = ws + 6 * M1;
    ushort_t* Zb    = (ushort_t*)(ws + 5 * M1);
    float* sumexp   = ws + 8 * M1;                    // 32768
    float* corr     = ws + 8 * M1 + H * S;            // 1024

    init_all<<<4129, 256, 0, stream>>>(attn_raw, (float*)d_out, sumexp, corr);

    convert_all<<<dim3(1024, 10), 256, 0, stream>>>(
        Qin, Kin, Vin, WQw, WKw, WVw, WOw,
        Qbin, Kbin, Vbin,
        wqkv, wqkv + (size_t)1024 * 1024, wqkv + (size_t)2 * 1024 * 1024, wob);

    gemm_qkv<<<dim3(48, 16), 256, 0, stream>>>(
        Qbin, Kbin, Vbin, wqkv, WQb, WKb, WVb, qbb, kbb, vt);

    attn_mfma<<<dim3(32, H), 512, 0, stream>>>(qbb, kbb, vt, attn_raw, sumexp);

    corr_kernel<<<256, 256, 0, stream>>>(sumexp, vt, corr);
    convert_Z<<<2048, 256, 0, stream>>>(attn_raw, corr, Zb);

    gemm_out<<<dim3(16, 16, 2), 256, 0, stream>>>(Zb, wob, WOb, (float*)d_out);
}